// Round 1
// baseline (389.030 us; speedup 1.0000x reference)
//
#include <hip/hip_runtime.h>

typedef __bf16 bf16;
typedef __bf16 bf16x4 __attribute__((ext_vector_type(4)));
typedef __bf16 bf16x8 __attribute__((ext_vector_type(8)));
typedef float floatx4 __attribute__((ext_vector_type(4)));

#define DD 768
#define NH 12
#define HDIM 64
#define BB 16
#define NN 1024
#define MTOT (BB*NN)   // 16384
#define WELEM (DD*DD)  // 589824

__device__ __forceinline__ void async_cp16(const void* g, void* l) {
  __builtin_amdgcn_global_load_lds((const __attribute__((address_space(1))) void*)g,
                                   (__attribute__((address_space(3))) void*)l, 16, 0, 0);
}

// ---------------- LayerNorm: x (f32) -> A (bf16) ----------------
__global__ __launch_bounds__(256) void ln_kernel(const float* __restrict__ x,
    const float* __restrict__ w, const float* __restrict__ b, bf16* __restrict__ A) {
  int row = blockIdx.x * 4 + (threadIdx.x >> 6);
  int lane = threadIdx.x & 63;
  const float4* xr = (const float4*)(x + (size_t)row * DD);
  float4 v[3];
  float s = 0.f;
#pragma unroll
  for (int i = 0; i < 3; i++) {
    v[i] = xr[lane + 64 * i];
    s += v[i].x + v[i].y + v[i].z + v[i].w;
  }
#pragma unroll
  for (int o = 32; o; o >>= 1) s += __shfl_xor(s, o);
  float mu = s * (1.f / 768.f);
  float vs = 0.f;
#pragma unroll
  for (int i = 0; i < 3; i++) {
    float dx;
    dx = v[i].x - mu; vs += dx * dx;
    dx = v[i].y - mu; vs += dx * dx;
    dx = v[i].z - mu; vs += dx * dx;
    dx = v[i].w - mu; vs += dx * dx;
  }
#pragma unroll
  for (int o = 32; o; o >>= 1) vs += __shfl_xor(vs, o);
  float rstd = rsqrtf(vs * (1.f / 768.f) + 1e-5f);
  const float4* wv = (const float4*)w;
  const float4* bv = (const float4*)b;
  bf16* Ar = A + (size_t)row * DD;
#pragma unroll
  for (int i = 0; i < 3; i++) {
    int c4 = lane + 64 * i;
    float4 ww = wv[c4], bb = bv[c4];
    bf16x4 pk;
    pk[0] = (bf16)((v[i].x - mu) * rstd * ww.x + bb.x);
    pk[1] = (bf16)((v[i].y - mu) * rstd * ww.y + bb.y);
    pk[2] = (bf16)((v[i].z - mu) * rstd * ww.z + bb.z);
    pk[3] = (bf16)((v[i].w - mu) * rstd * ww.w + bb.w);
    *(bf16x4*)(Ar + c4 * 4) = pk;
  }
}

// ---------------- Convert the 5 weight matrices f32 -> bf16 ----------------
__global__ __launch_bounds__(256) void convw_kernel(const float* __restrict__ w0,
    const float* __restrict__ w1, const float* __restrict__ w2,
    const float* __restrict__ w3, const float* __restrict__ w4, bf16* __restrict__ out) {
  int i = blockIdx.x * 256 + threadIdx.x;   // one per 4 elems; 737280 total
  int which = i / (WELEM / 4);
  int off = (i % (WELEM / 4)) * 4;
  const float* s = which == 0 ? w0 : which == 1 ? w1 : which == 2 ? w2 : which == 3 ? w3 : w4;
  float4 v = *(const float4*)(s + off);
  bf16x4 pk;
  pk[0] = (bf16)v.x; pk[1] = (bf16)v.y; pk[2] = (bf16)v.z; pk[3] = (bf16)v.w;
  *(bf16x4*)(out + (size_t)i * 4) = pk;
}

// ---------------- GEMM: C[m][n] = sum_k A[m][k] * W[n][k] (+bias, epilogue) -------
// EPI: 0 relu->bf16, 1 plain->bf16, 2 transposed (B,H,HD,N) store->bf16,
//      3 sigmoid->bf16, 4 final: Cf = X + Gate*(acc+bias) (f32)
template<int EPI>
__global__ __launch_bounds__(256) void gemm_kernel(
    const bf16* __restrict__ Aop, const bf16* __restrict__ W,
    const float* __restrict__ bias,
    bf16* __restrict__ Cb, float* __restrict__ Cf,
    const float* __restrict__ Xres, const bf16* __restrict__ Gate) {
  __shared__ bf16 As[128 * 32];
  __shared__ bf16 Bs[128 * 32];
  int tid = threadIdx.x;
  int wave = tid >> 6, lane = tid & 63;
  int quad = lane >> 4, l16 = lane & 15;
  int wm = wave & 1, wn = wave >> 1;
  int bn = blockIdx.x, bm = blockIdx.y;
  int srow = lane >> 2, scol = (lane & 3) * 8;

  const bf16* Ag = Aop + (size_t)(bm * 128 + srow) * DD + scol;
  const bf16* Bg = W + (size_t)(bn * 128 + srow) * DD + scol;

  floatx4 acc[4][4];
#pragma unroll
  for (int i = 0; i < 4; i++)
#pragma unroll
    for (int j = 0; j < 4; j++)
      acc[i][j] = (floatx4){0.f, 0.f, 0.f, 0.f};

  for (int k0 = 0; k0 < DD; k0 += 32) {
    __syncthreads();
#pragma unroll
    for (int it = 0; it < 2; it++) {
      int r0 = (it * 4 + wave) * 16;
      async_cp16(Ag + (size_t)r0 * DD + k0, &As[r0 * 32]);
      async_cp16(Bg + (size_t)r0 * DD + k0, &Bs[r0 * 32]);
    }
    __syncthreads();
    bf16x8 a[4], b[4];
#pragma unroll
    for (int i = 0; i < 4; i++) a[i] = *(const bf16x8*)&As[(wm * 64 + i * 16 + l16) * 32 + quad * 8];
#pragma unroll
    for (int i = 0; i < 4; i++) b[i] = *(const bf16x8*)&Bs[(wn * 64 + i * 16 + l16) * 32 + quad * 8];
#pragma unroll
    for (int mi = 0; mi < 4; mi++)
#pragma unroll
      for (int ni = 0; ni < 4; ni++)
        acc[mi][ni] = __builtin_amdgcn_mfma_f32_16x16x32_bf16(a[mi], b[ni], acc[mi][ni], 0, 0, 0);
  }

#pragma unroll
  for (int ni = 0; ni < 4; ni++) {
    int gc = bn * 128 + wn * 64 + ni * 16 + l16;
    float bz = bias[gc];
#pragma unroll
    for (int mi = 0; mi < 4; mi++) {
      int gm0 = bm * 128 + wm * 64 + mi * 16 + quad * 4;
      if (EPI == 2) {
        int h = gc >> 6, dd2 = gc & 63;
        int b_ = gm0 >> 10, n0 = gm0 & 1023;
        bf16x4 pk;
#pragma unroll
        for (int r = 0; r < 4; r++) pk[r] = (bf16)(acc[mi][ni][r] + bz);
        *(bf16x4*)&Cb[(((size_t)b_ * NH + h) * HDIM + dd2) * NN + n0] = pk;
      } else {
#pragma unroll
        for (int r = 0; r < 4; r++) {
          float v = acc[mi][ni][r] + bz;
          size_t idx = (size_t)(gm0 + r) * DD + gc;
          if (EPI == 0) Cb[idx] = (bf16)fmaxf(v, 0.f);
          else if (EPI == 1) Cb[idx] = (bf16)v;
          else if (EPI == 3) Cb[idx] = (bf16)(1.f / (1.f + __expf(-v)));
          else { float g = (float)Gate[idx]; Cf[idx] = Xres[idx] + g * v; }
        }
      }
    }
  }
}

// ---------------- RoPE: QKraw (B,N,H,HD) -> QKr (same) + QKrT (B,H,HD,N) ------
__global__ __launch_bounds__(256) void rope_kernel(const bf16* __restrict__ QKraw,
    const float* __restrict__ rope, bf16* __restrict__ QKr, bf16* __restrict__ QKrT) {
  int blk = blockIdx.x;
  int bh = blk >> 7;       // /128
  int nc = blk & 127;
  int b_ = bh / NH, h_ = bh % NH;
  int t = threadIdx.x;
  int noff = t >> 5;       // 0..7
  int d = t & 31;
  int n = nc * 8 + noff;
  size_t ibase = ((size_t)(b_ * NN + n)) * DD + h_ * HDIM;
  float x1 = (float)QKraw[ibase + 2 * d];
  float x2 = (float)QKraw[ibase + 2 * d + 1];
  float a0 = rope[n * HDIM + 2 * d];
  float a1 = rope[n * HDIM + 2 * d + 1];
  float o1 = x1 * __cosf(a0) - x2 * __sinf(a0);
  float o2 = x1 * __sinf(a1) + x2 * __cosf(a1);
  size_t obase = ((size_t)(b_ * NN + n)) * DD + h_ * HDIM;
  QKr[obase + d] = (bf16)o1;
  QKr[obase + 32 + d] = (bf16)o2;
  size_t tbase = ((size_t)bh * HDIM + d) * NN + n;
  QKrT[tbase] = (bf16)o1;
  QKrT[tbase + (size_t)32 * NN] = (bf16)o2;
}

// ---------------- Attention: T = QKr^T @ V (64x64), attn = QKr @ T / 8 --------
__global__ __launch_bounds__(256) void attn_kernel(const bf16* __restrict__ QKr,
    const bf16* __restrict__ QKrT, const bf16* __restrict__ VT, bf16* __restrict__ attn) {
  __shared__ float Tp[64][64];
  __shared__ bf16 Tbf[64][72];
  int bh = blockIdx.x;
  int tid = threadIdx.x, wave = tid >> 6, lane = tid & 63;
  int quad = lane >> 4, l16 = lane & 15;
  const bf16* Qt = QKrT + (size_t)bh * (HDIM * NN);
  const bf16* Vt = VT + (size_t)bh * (HDIM * NN);

  floatx4 acc[4][4];
#pragma unroll
  for (int i = 0; i < 4; i++)
#pragma unroll
    for (int j = 0; j < 4; j++)
      acc[i][j] = (floatx4){0.f, 0.f, 0.f, 0.f};

  int kbase = wave * 256;
#pragma unroll
  for (int k0 = 0; k0 < 256; k0 += 32) {
    bf16x8 a[4], b[4];
#pragma unroll
    for (int i = 0; i < 4; i++) a[i] = *(const bf16x8*)&Qt[(size_t)(i * 16 + l16) * NN + kbase + k0 + quad * 8];
#pragma unroll
    for (int i = 0; i < 4; i++) b[i] = *(const bf16x8*)&Vt[(size_t)(i * 16 + l16) * NN + kbase + k0 + quad * 8];
#pragma unroll
    for (int mi = 0; mi < 4; mi++)
#pragma unroll
      for (int ni = 0; ni < 4; ni++)
        acc[mi][ni] = __builtin_amdgcn_mfma_f32_16x16x32_bf16(a[mi], b[ni], acc[mi][ni], 0, 0, 0);
  }
  // reduce partials across the 4 waves (k-split)
#pragma unroll
  for (int w = 0; w < 4; w++) {
    if (wave == w) {
#pragma unroll
      for (int mi = 0; mi < 4; mi++)
#pragma unroll
        for (int ni = 0; ni < 4; ni++)
#pragma unroll
          for (int r = 0; r < 4; r++) {
            float val = acc[mi][ni][r];
            float* p = &Tp[mi * 16 + quad * 4 + r][ni * 16 + l16];
            if (w == 0) *p = val; else *p += val;
          }
    }
    __syncthreads();
  }
  // transpose + scale into bf16 (Tbf[d2][d1] = T[d1][d2]/8)
  for (int e = tid; e < 4096; e += 256) {
    int d1 = e >> 6, d2 = e & 63;
    Tbf[d2][d1] = (bf16)(Tp[d1][d2] * 0.125f);
  }
  __syncthreads();

  // stage 2: attn[n][d2] = sum_d1 QKr[n][d1] * Tbf[d2][d1]
  int b_ = bh / NH, h_ = bh % NH;
  const bf16* Q = QKr + (size_t)(b_ * NN) * DD + h_ * HDIM;
  bf16* Ao = attn + (size_t)(b_ * NN) * DD + h_ * HDIM;
  bf16x8 Bf[4][2];
#pragma unroll
  for (int ni = 0; ni < 4; ni++)
#pragma unroll
    for (int ks = 0; ks < 2; ks++)
      Bf[ni][ks] = *(const bf16x8*)&Tbf[ni * 16 + l16][ks * 32 + quad * 8];

  for (int mi = 0; mi < 16; mi++) {
    int nrow = wave * 256 + mi * 16;
    bf16x8 a0 = *(const bf16x8*)&Q[(size_t)(nrow + l16) * DD + quad * 8];
    bf16x8 a1 = *(const bf16x8*)&Q[(size_t)(nrow + l16) * DD + 32 + quad * 8];
    floatx4 o[4];
#pragma unroll
    for (int ni = 0; ni < 4; ni++) o[ni] = (floatx4){0.f, 0.f, 0.f, 0.f};
#pragma unroll
    for (int ni = 0; ni < 4; ni++) {
      o[ni] = __builtin_amdgcn_mfma_f32_16x16x32_bf16(a0, Bf[ni][0], o[ni], 0, 0, 0);
      o[ni] = __builtin_amdgcn_mfma_f32_16x16x32_bf16(a1, Bf[ni][1], o[ni], 0, 0, 0);
    }
#pragma unroll
    for (int ni = 0; ni < 4; ni++)
#pragma unroll
      for (int r = 0; r < 4; r++)
        Ao[(size_t)(nrow + quad * 4 + r) * DD + ni * 16 + l16] = (bf16)o[ni][r];
  }
}

extern "C" void kernel_launch(void* const* d_in, const int* in_sizes, int n_in,
                              void* d_out, int out_size, void* d_ws, size_t ws_size,
                              hipStream_t stream) {
  const float* x      = (const float*)d_in[0];
  const float* rope   = (const float*)d_in[1];
  const float* ln_w   = (const float*)d_in[2];
  const float* ln_b   = (const float*)d_in[3];
  const float* enc_w  = (const float*)d_in[4];
  const float* enc_b  = (const float*)d_in[5];
  const float* qk_w   = (const float*)d_in[6];
  const float* qk_b   = (const float*)d_in[7];
  const float* v_w    = (const float*)d_in[8];
  const float* v_b    = (const float*)d_in[9];
  const float* out_w  = (const float*)d_in[10];
  const float* out_b  = (const float*)d_in[11];
  const float* gate_w = (const float*)d_in[12];
  const float* gate_b = (const float*)d_in[13];

  char* w = (char*)d_ws;
  const size_t S = (size_t)MTOT * DD * 2;  // 25165824 bytes per bf16 (M,768) buffer
  bf16* A     = (bf16*)(w);
  bf16* L     = (bf16*)(w + S);        // later reused as attn buffer
  bf16* QKraw = (bf16*)(w + 2 * S);    // later reused as gate buffer
  bf16* QKr   = (bf16*)(w + 3 * S);
  bf16* QKrT  = (bf16*)(w + 4 * S);
  bf16* VT    = (bf16*)(w + 5 * S);
  bf16* Wb    = (bf16*)(w + 6 * S);    // 5 x 589824 bf16
  bf16* Gate  = QKraw;
  bf16* attnb = L;

  ln_kernel<<<dim3(MTOT / 4), dim3(256), 0, stream>>>(x, ln_w, ln_b, A);
  convw_kernel<<<dim3(5 * WELEM / 4 / 256), dim3(256), 0, stream>>>(enc_w, qk_w, v_w, out_w, gate_w, Wb);

  dim3 ggrid(DD / 128, MTOT / 128);  // (6, 128)
  // L = relu(A @ enc^T + b)
  gemm_kernel<0><<<ggrid, dim3(256), 0, stream>>>(A, Wb + 0 * (size_t)WELEM, enc_b, L, nullptr, nullptr, nullptr);
  // QKraw = L @ qk^T + b
  gemm_kernel<1><<<ggrid, dim3(256), 0, stream>>>(L, Wb + 1 * (size_t)WELEM, qk_b, QKraw, nullptr, nullptr, nullptr);
  // RoPE -> QKr, QKrT
  rope_kernel<<<dim3(BB * NH * 128), dim3(256), 0, stream>>>(QKraw, rope, QKr, QKrT);
  // VT = (L @ v^T + b) stored transposed (B,H,HD,N)
  gemm_kernel<2><<<ggrid, dim3(256), 0, stream>>>(L, Wb + 2 * (size_t)WELEM, v_b, VT, nullptr, nullptr, nullptr);
  // Gate = sigmoid(A @ gate^T + b)  (into QKraw slot, now dead)
  gemm_kernel<3><<<ggrid, dim3(256), 0, stream>>>(A, Wb + 4 * (size_t)WELEM, gate_b, Gate, nullptr, nullptr, nullptr);
  // attn = QKr @ (QKr^T @ V) / 8  (into L slot, now dead)
  attn_kernel<<<dim3(BB * NH), dim3(256), 0, stream>>>(QKr, QKrT, VT, attnb);
  // out = x + Gate * (attn @ out^T + b)
  gemm_kernel<4><<<ggrid, dim3(256), 0, stream>>>(attnb, Wb + 3 * (size_t)WELEM, out_b, nullptr, (float*)d_out, x, Gate);
}

// Round 2
// 360.027 us; speedup vs baseline: 1.0806x; 1.0806x over previous
//
#include <hip/hip_runtime.h>

typedef __bf16 bf16;
typedef __bf16 bf16x4 __attribute__((ext_vector_type(4)));
typedef __bf16 bf16x8 __attribute__((ext_vector_type(8)));
typedef float floatx4 __attribute__((ext_vector_type(4)));

#define DD 768
#define NH 12
#define HDIM 64
#define BB 16
#define NN 1024
#define MTOT (BB*NN)   // 16384
#define WELEM (DD*DD)  // 589824

__device__ __forceinline__ void async_cp16(const void* g, void* l) {
  __builtin_amdgcn_global_load_lds((const __attribute__((address_space(1))) void*)g,
                                   (__attribute__((address_space(3))) void*)l, 16, 0, 0);
}

// ---------------- LayerNorm: x (f32) -> A (bf16) ----------------
__global__ __launch_bounds__(256) void ln_kernel(const float* __restrict__ x,
    const float* __restrict__ w, const float* __restrict__ b, bf16* __restrict__ A) {
  int row = blockIdx.x * 4 + (threadIdx.x >> 6);
  int lane = threadIdx.x & 63;
  const float4* xr = (const float4*)(x + (size_t)row * DD);
  float4 v[3];
  float s = 0.f;
#pragma unroll
  for (int i = 0; i < 3; i++) {
    v[i] = xr[lane + 64 * i];
    s += v[i].x + v[i].y + v[i].z + v[i].w;
  }
#pragma unroll
  for (int o = 32; o; o >>= 1) s += __shfl_xor(s, o);
  float mu = s * (1.f / 768.f);
  float vs = 0.f;
#pragma unroll
  for (int i = 0; i < 3; i++) {
    float dx;
    dx = v[i].x - mu; vs += dx * dx;
    dx = v[i].y - mu; vs += dx * dx;
    dx = v[i].z - mu; vs += dx * dx;
    dx = v[i].w - mu; vs += dx * dx;
  }
#pragma unroll
  for (int o = 32; o; o >>= 1) vs += __shfl_xor(vs, o);
  float rstd = rsqrtf(vs * (1.f / 768.f) + 1e-5f);
  const float4* wv = (const float4*)w;
  const float4* bv = (const float4*)b;
  bf16* Ar = A + (size_t)row * DD;
#pragma unroll
  for (int i = 0; i < 3; i++) {
    int c4 = lane + 64 * i;
    float4 ww = wv[c4], bb = bv[c4];
    bf16x4 pk;
    pk[0] = (bf16)((v[i].x - mu) * rstd * ww.x + bb.x);
    pk[1] = (bf16)((v[i].y - mu) * rstd * ww.y + bb.y);
    pk[2] = (bf16)((v[i].z - mu) * rstd * ww.z + bb.z);
    pk[3] = (bf16)((v[i].w - mu) * rstd * ww.w + bb.w);
    *(bf16x4*)(Ar + c4 * 4) = pk;
  }
}

// ------- Convert weights f32 -> bf16, order: enc, gate, qk, v, out -------
__global__ __launch_bounds__(256) void convw_kernel(const float* __restrict__ w0,
    const float* __restrict__ w1, const float* __restrict__ w2,
    const float* __restrict__ w3, const float* __restrict__ w4, bf16* __restrict__ out) {
  int i = blockIdx.x * 256 + threadIdx.x;   // one per 4 elems; 737280 total
  int which = i / (WELEM / 4);
  int off = (i % (WELEM / 4)) * 4;
  const float* s = which == 0 ? w0 : which == 1 ? w1 : which == 2 ? w2 : which == 3 ? w3 : w4;
  float4 v = *(const float4*)(s + off);
  bf16x4 pk;
  pk[0] = (bf16)v.x; pk[1] = (bf16)v.y; pk[2] = (bf16)v.z; pk[3] = (bf16)v.w;
  *(bf16x4*)(out + (size_t)i * 4) = pk;
}

// ---------------- GEMM body: C[m][n] = sum_k A[m][k] * W[n][k] (+bias, epilogue) ---
// EPI: 0 relu->bf16, 1 plain->bf16, 2 transposed (B,H,HD,N) store->bf16,
//      3 sigmoid->bf16, 4 final: Cf = X + Gate*(acc+bias) (f32)
// For EPI != 2 the MFMA operands are SWAPPED (computes C^T in-register), so each
// lane holds 1 output row x 4 consecutive cols -> packed coalesced stores.
template<int EPI>
__device__ __forceinline__ void gemm_body(
    int bm, int bn, int bnl,
    const bf16* __restrict__ Aop, const bf16* __restrict__ W,
    const float* __restrict__ bias,
    bf16* __restrict__ Cb, float* __restrict__ Cf,
    const float* __restrict__ Xres, const bf16* __restrict__ Gate,
    bf16* As, bf16* Bs) {
  int tid = threadIdx.x;
  int wave = tid >> 6, lane = tid & 63;
  int quad = lane >> 4, l16 = lane & 15;
  int wm = wave & 1, wn = wave >> 1;
  int srow = lane >> 2, scol = (lane & 3) * 8;

  const bf16* Ag = Aop + (size_t)(bm * 128 + srow) * DD + scol;
  const bf16* Bg = W + (size_t)(bn * 128 + srow) * DD + scol;

  floatx4 acc[4][4];
#pragma unroll
  for (int i = 0; i < 4; i++)
#pragma unroll
    for (int j = 0; j < 4; j++)
      acc[i][j] = (floatx4){0.f, 0.f, 0.f, 0.f};

  for (int k0 = 0; k0 < DD; k0 += 32) {
    __syncthreads();
#pragma unroll
    for (int it = 0; it < 2; it++) {
      int r0 = (it * 4 + wave) * 16;
      async_cp16(Ag + (size_t)r0 * DD + k0, &As[r0 * 32]);
      async_cp16(Bg + (size_t)r0 * DD + k0, &Bs[r0 * 32]);
    }
    __syncthreads();
    bf16x8 a[4], b[4];
#pragma unroll
    for (int i = 0; i < 4; i++) a[i] = *(const bf16x8*)&As[(wm * 64 + i * 16 + l16) * 32 + quad * 8];
#pragma unroll
    for (int i = 0; i < 4; i++) b[i] = *(const bf16x8*)&Bs[(wn * 64 + i * 16 + l16) * 32 + quad * 8];
    if (EPI == 2) {
#pragma unroll
      for (int mi = 0; mi < 4; mi++)
#pragma unroll
        for (int ni = 0; ni < 4; ni++)
          acc[mi][ni] = __builtin_amdgcn_mfma_f32_16x16x32_bf16(a[mi], b[ni], acc[mi][ni], 0, 0, 0);
    } else {
      // swapped: acc[mi][ni] = (C^T tile) -> lane holds row m = l16, cols n = quad*4+r
#pragma unroll
      for (int mi = 0; mi < 4; mi++)
#pragma unroll
        for (int ni = 0; ni < 4; ni++)
          acc[mi][ni] = __builtin_amdgcn_mfma_f32_16x16x32_bf16(b[ni], a[mi], acc[mi][ni], 0, 0, 0);
    }
  }

  if (EPI == 2) {
#pragma unroll
    for (int ni = 0; ni < 4; ni++) {
      int gc = bnl * 128 + wn * 64 + ni * 16 + l16;   // 0..767 within V half
      float bz = bias[gc];
      int h = gc >> 6, dd2 = gc & 63;
#pragma unroll
      for (int mi = 0; mi < 4; mi++) {
        int gm0 = bm * 128 + wm * 64 + mi * 16 + quad * 4;
        int b_ = gm0 >> 10, n0 = gm0 & 1023;
        bf16x4 pk;
#pragma unroll
        for (int r = 0; r < 4; r++) pk[r] = (bf16)(acc[mi][ni][r] + bz);
        *(bf16x4*)&Cb[(((size_t)b_ * NH + h) * HDIM + dd2) * NN + n0] = pk;
      }
    }
  } else {
#pragma unroll
    for (int mi = 0; mi < 4; mi++) {
      int gm = bm * 128 + wm * 64 + mi * 16 + l16;
#pragma unroll
      for (int ni = 0; ni < 4; ni++) {
        int gc = bnl * 128 + wn * 64 + ni * 16 + quad * 4;
        float4 bz = *(const float4*)&bias[gc];
        float v0 = acc[mi][ni][0] + bz.x;
        float v1 = acc[mi][ni][1] + bz.y;
        float v2 = acc[mi][ni][2] + bz.z;
        float v3 = acc[mi][ni][3] + bz.w;
        size_t idx = (size_t)gm * DD + gc;
        if (EPI == 4) {
          bf16x4 g = *(const bf16x4*)&Gate[idx];
          float4 xr = *(const float4*)&Xres[idx];
          float4 o;
          o.x = xr.x + (float)g[0] * v0;
          o.y = xr.y + (float)g[1] * v1;
          o.z = xr.z + (float)g[2] * v2;
          o.w = xr.w + (float)g[3] * v3;
          *(float4*)&Cf[idx] = o;
        } else {
          bf16x4 pk;
          if (EPI == 0) {
            pk[0] = (bf16)fmaxf(v0, 0.f); pk[1] = (bf16)fmaxf(v1, 0.f);
            pk[2] = (bf16)fmaxf(v2, 0.f); pk[3] = (bf16)fmaxf(v3, 0.f);
          } else if (EPI == 1) {
            pk[0] = (bf16)v0; pk[1] = (bf16)v1; pk[2] = (bf16)v2; pk[3] = (bf16)v3;
          } else {  // EPI == 3 sigmoid
            pk[0] = (bf16)(1.f / (1.f + __expf(-v0)));
            pk[1] = (bf16)(1.f / (1.f + __expf(-v1)));
            pk[2] = (bf16)(1.f / (1.f + __expf(-v2)));
            pk[3] = (bf16)(1.f / (1.f + __expf(-v3)));
          }
          *(bf16x4*)&Cb[idx] = pk;
        }
      }
    }
  }
}

// NBN = n-tiles per bm (6 for N=768, 12 for fused N=1536; bn>=6 -> HI half).
// 1D grid with XCD swizzle: xcd = blk&7 owns bm range [xcd*16, xcd*16+16).
template<int EPI_LO, int EPI_HI, int NBN>
__global__ __launch_bounds__(256) void gemm_kernel(
    const bf16* __restrict__ Aop, const bf16* __restrict__ W,
    const float* __restrict__ bias_lo, const float* __restrict__ bias_hi,
    bf16* __restrict__ C_lo, bf16* __restrict__ C_hi, float* __restrict__ Cf,
    const float* __restrict__ Xres, const bf16* __restrict__ Gate) {
  __shared__ bf16 As[128 * 32];
  __shared__ bf16 Bs[128 * 32];
  int blk = blockIdx.x;
  int xcd = blk & 7, slot = blk >> 3;
  int bm = xcd * 16 + slot / NBN;
  int bn = slot % NBN;
  if (NBN == 12 && bn >= 6) {
    gemm_body<EPI_HI>(bm, bn, bn - 6, Aop, W, bias_hi, C_hi, Cf, Xres, Gate, As, Bs);
  } else {
    gemm_body<EPI_LO>(bm, bn, bn, Aop, W, bias_lo, C_lo, Cf, Xres, Gate, As, Bs);
  }
}

// ---------------- RoPE: QKraw (B,N,H,HD) -> QKr (same) + QKrT (B,H,HD,N) ------
__global__ __launch_bounds__(256) void rope_kernel(const bf16* __restrict__ QKraw,
    const float* __restrict__ rope, bf16* __restrict__ QKr, bf16* __restrict__ QKrT) {
  int blk = blockIdx.x;
  int bh = blk >> 7;       // /128
  int nc = blk & 127;
  int b_ = bh / NH, h_ = bh % NH;
  int t = threadIdx.x;
  int noff = t >> 5;       // 0..7
  int d = t & 31;
  int n = nc * 8 + noff;
  size_t ibase = ((size_t)(b_ * NN + n)) * DD + h_ * HDIM;
  float x1 = (float)QKraw[ibase + 2 * d];
  float x2 = (float)QKraw[ibase + 2 * d + 1];
  float a0 = rope[n * HDIM + 2 * d];
  float a1 = rope[n * HDIM + 2 * d + 1];
  float o1 = x1 * __cosf(a0) - x2 * __sinf(a0);
  float o2 = x1 * __sinf(a1) + x2 * __cosf(a1);
  size_t obase = ((size_t)(b_ * NN + n)) * DD + h_ * HDIM;
  QKr[obase + d] = (bf16)o1;
  QKr[obase + 32 + d] = (bf16)o2;
  size_t tbase = ((size_t)bh * HDIM + d) * NN + n;
  QKrT[tbase] = (bf16)o1;
  QKrT[tbase + (size_t)32 * NN] = (bf16)o2;
}

// ---------------- Attention: T = QKr^T @ V (64x64), attn = QKr @ T / 8 --------
__global__ __launch_bounds__(256) void attn_kernel(const bf16* __restrict__ QKr,
    const bf16* __restrict__ QKrT, const bf16* __restrict__ VT, bf16* __restrict__ attn) {
  __shared__ float Tp[64][64];
  __shared__ bf16 Tbf[64][72];
  int bh = blockIdx.x;
  int tid = threadIdx.x, wave = tid >> 6, lane = tid & 63;
  int quad = lane >> 4, l16 = lane & 15;
  const bf16* Qt = QKrT + (size_t)bh * (HDIM * NN);
  const bf16* Vt = VT + (size_t)bh * (HDIM * NN);

  floatx4 acc[4][4];
#pragma unroll
  for (int i = 0; i < 4; i++)
#pragma unroll
    for (int j = 0; j < 4; j++)
      acc[i][j] = (floatx4){0.f, 0.f, 0.f, 0.f};

  int kbase = wave * 256;
#pragma unroll
  for (int k0 = 0; k0 < 256; k0 += 32) {
    bf16x8 a[4], b[4];
#pragma unroll
    for (int i = 0; i < 4; i++) a[i] = *(const bf16x8*)&Qt[(size_t)(i * 16 + l16) * NN + kbase + k0 + quad * 8];
#pragma unroll
    for (int i = 0; i < 4; i++) b[i] = *(const bf16x8*)&Vt[(size_t)(i * 16 + l16) * NN + kbase + k0 + quad * 8];
#pragma unroll
    for (int mi = 0; mi < 4; mi++)
#pragma unroll
      for (int ni = 0; ni < 4; ni++)
        acc[mi][ni] = __builtin_amdgcn_mfma_f32_16x16x32_bf16(a[mi], b[ni], acc[mi][ni], 0, 0, 0);
  }
  // reduce partials across the 4 waves (k-split)
#pragma unroll
  for (int w = 0; w < 4; w++) {
    if (wave == w) {
#pragma unroll
      for (int mi = 0; mi < 4; mi++)
#pragma unroll
        for (int ni = 0; ni < 4; ni++)
#pragma unroll
          for (int r = 0; r < 4; r++) {
            float val = acc[mi][ni][r];
            float* p = &Tp[mi * 16 + quad * 4 + r][ni * 16 + l16];
            if (w == 0) *p = val; else *p += val;
          }
    }
    __syncthreads();
  }
  // transpose + scale into bf16 (Tbf[d2][d1] = T[d1][d2]/8)
  for (int e = tid; e < 4096; e += 256) {
    int d1 = e >> 6, d2 = e & 63;
    Tbf[d2][d1] = (bf16)(Tp[d1][d2] * 0.125f);
  }
  __syncthreads();

  // stage 2: attn[n][d2] = sum_d1 QKr[n][d1] * Tbf[d2][d1]
  int b_ = bh / NH, h_ = bh % NH;
  const bf16* Q = QKr + (size_t)(b_ * NN) * DD + h_ * HDIM;
  bf16* Ao = attn + (size_t)(b_ * NN) * DD + h_ * HDIM;
  bf16x8 Bf[4][2];
#pragma unroll
  for (int ni = 0; ni < 4; ni++)
#pragma unroll
    for (int ks = 0; ks < 2; ks++)
      Bf[ni][ks] = *(const bf16x8*)&Tbf[ni * 16 + l16][ks * 32 + quad * 8];

  for (int mi = 0; mi < 16; mi++) {
    int nrow = wave * 256 + mi * 16;
    bf16x8 a0 = *(const bf16x8*)&Q[(size_t)(nrow + l16) * DD + quad * 8];
    bf16x8 a1 = *(const bf16x8*)&Q[(size_t)(nrow + l16) * DD + 32 + quad * 8];
    floatx4 o[4];
#pragma unroll
    for (int ni = 0; ni < 4; ni++) o[ni] = (floatx4){0.f, 0.f, 0.f, 0.f};
#pragma unroll
    for (int ni = 0; ni < 4; ni++) {
      o[ni] = __builtin_amdgcn_mfma_f32_16x16x32_bf16(a0, Bf[ni][0], o[ni], 0, 0, 0);
      o[ni] = __builtin_amdgcn_mfma_f32_16x16x32_bf16(a1, Bf[ni][1], o[ni], 0, 0, 0);
    }
#pragma unroll
    for (int ni = 0; ni < 4; ni++)
#pragma unroll
      for (int r = 0; r < 4; r++)
        Ao[(size_t)(nrow + quad * 4 + r) * DD + ni * 16 + l16] = (bf16)o[ni][r];
  }
}

extern "C" void kernel_launch(void* const* d_in, const int* in_sizes, int n_in,
                              void* d_out, int out_size, void* d_ws, size_t ws_size,
                              hipStream_t stream) {
  const float* x      = (const float*)d_in[0];
  const float* rope   = (const float*)d_in[1];
  const float* ln_w   = (const float*)d_in[2];
  const float* ln_b   = (const float*)d_in[3];
  const float* enc_w  = (const float*)d_in[4];
  const float* enc_b  = (const float*)d_in[5];
  const float* qk_w   = (const float*)d_in[6];
  const float* qk_b   = (const float*)d_in[7];
  const float* v_w    = (const float*)d_in[8];
  const float* v_b    = (const float*)d_in[9];
  const float* out_w  = (const float*)d_in[10];
  const float* out_b  = (const float*)d_in[11];
  const float* gate_w = (const float*)d_in[12];
  const float* gate_b = (const float*)d_in[13];

  char* w = (char*)d_ws;
  const size_t S = (size_t)MTOT * DD * 2;  // 25165824 bytes per bf16 (M,768) buffer
  bf16* s0 = (bf16*)(w);           // A, then QKraw (after GEMM1 A is dead... A dead after GEMM1; QKraw written by GEMM2)
  bf16* s1 = (bf16*)(w + S);       // L, then attnb
  bf16* s2 = (bf16*)(w + 2 * S);   // Gate
  bf16* s3 = (bf16*)(w + 3 * S);   // QKr
  bf16* s4 = (bf16*)(w + 4 * S);   // QKrT
  bf16* s5 = (bf16*)(w + 5 * S);   // VT
  bf16* Wb = (bf16*)(w + 6 * S);   // weights bf16: enc, gate, qk, v, out

  bf16* A = s0;
  bf16* L = s1;
  bf16* Gate = s2;
  bf16* QKraw = s0;   // reuses A slot (A consumed by GEMM1 before GEMM2 runs)
  bf16* QKr = s3;
  bf16* QKrT = s4;
  bf16* VT = s5;
  bf16* attnb = s1;   // reuses L slot (L consumed by GEMM2 before attn runs)

  ln_kernel<<<dim3(MTOT / 4), dim3(256), 0, stream>>>(x, ln_w, ln_b, A);
  convw_kernel<<<dim3(5 * WELEM / 4 / 256), dim3(256), 0, stream>>>(enc_w, gate_w, qk_w, v_w, out_w, Wb);

  // GEMM1: [L | Gate] = [relu | sigmoid](A @ [enc; gate]^T + b)   (N=1536 fused)
  gemm_kernel<0, 3, 12><<<dim3(1536), dim3(256), 0, stream>>>(
      A, Wb, enc_b, gate_b, L, Gate, nullptr, nullptr, nullptr);
  // GEMM2: [QKraw | VT] = L @ [qk; v]^T + b   (VT stored transposed (B,H,HD,N))
  gemm_kernel<1, 2, 12><<<dim3(1536), dim3(256), 0, stream>>>(
      L, Wb + 2 * (size_t)WELEM, qk_b, v_b, QKraw, VT, nullptr, nullptr, nullptr);
  // RoPE -> QKr, QKrT
  rope_kernel<<<dim3(BB * NH * 128), dim3(256), 0, stream>>>(QKraw, rope, QKr, QKrT);
  // attn = QKr @ (QKr^T @ V) / 8
  attn_kernel<<<dim3(BB * NH), dim3(256), 0, stream>>>(QKr, QKrT, VT, attnb);
  // GEMM3: out = x + Gate * (attnb @ out_w^T + b)   (f32 out)
  gemm_kernel<4, 4, 6><<<dim3(768), dim3(256), 0, stream>>>(
      attnb, Wb + 4 * (size_t)WELEM, out_b, nullptr, nullptr, nullptr, (float*)d_out, x, Gate);
}

// Round 3
// 339.762 us; speedup vs baseline: 1.1450x; 1.0596x over previous
//
#include <hip/hip_runtime.h>

typedef __bf16 bf16;
typedef __bf16 bf16x4 __attribute__((ext_vector_type(4)));
typedef __bf16 bf16x8 __attribute__((ext_vector_type(8)));
typedef float floatx4 __attribute__((ext_vector_type(4)));

#define DD 768
#define NH 12
#define HDIM 64
#define BB 16
#define NN 1024
#define MTOT (BB*NN)   // 16384
#define WELEM (DD*DD)  // 589824

__device__ __forceinline__ void async_cp16(const void* g, void* l) {
  __builtin_amdgcn_global_load_lds((const __attribute__((address_space(1))) void*)g,
                                   (__attribute__((address_space(3))) void*)l, 16, 0, 0);
}

// ---------------- LayerNorm: x (f32) -> A (bf16) ----------------
__global__ __launch_bounds__(256) void ln_kernel(const float* __restrict__ x,
    const float* __restrict__ w, const float* __restrict__ b, bf16* __restrict__ A) {
  int row = blockIdx.x * 4 + (threadIdx.x >> 6);
  int lane = threadIdx.x & 63;
  const float4* xr = (const float4*)(x + (size_t)row * DD);
  float4 v[3];
  float s = 0.f;
#pragma unroll
  for (int i = 0; i < 3; i++) {
    v[i] = xr[lane + 64 * i];
    s += v[i].x + v[i].y + v[i].z + v[i].w;
  }
#pragma unroll
  for (int o = 32; o; o >>= 1) s += __shfl_xor(s, o);
  float mu = s * (1.f / 768.f);
  float vs = 0.f;
#pragma unroll
  for (int i = 0; i < 3; i++) {
    float dx;
    dx = v[i].x - mu; vs += dx * dx;
    dx = v[i].y - mu; vs += dx * dx;
    dx = v[i].z - mu; vs += dx * dx;
    dx = v[i].w - mu; vs += dx * dx;
  }
#pragma unroll
  for (int o = 32; o; o >>= 1) vs += __shfl_xor(vs, o);
  float rstd = rsqrtf(vs * (1.f / 768.f) + 1e-5f);
  const float4* wv = (const float4*)w;
  const float4* bv = (const float4*)b;
  bf16* Ar = A + (size_t)row * DD;
#pragma unroll
  for (int i = 0; i < 3; i++) {
    int c4 = lane + 64 * i;
    float4 ww = wv[c4], bb = bv[c4];
    bf16x4 pk;
    pk[0] = (bf16)((v[i].x - mu) * rstd * ww.x + bb.x);
    pk[1] = (bf16)((v[i].y - mu) * rstd * ww.y + bb.y);
    pk[2] = (bf16)((v[i].z - mu) * rstd * ww.z + bb.z);
    pk[3] = (bf16)((v[i].w - mu) * rstd * ww.w + bb.w);
    *(bf16x4*)(Ar + c4 * 4) = pk;
  }
}

// ------- Convert weights f32 -> bf16, order: enc, gate, qk, v, out -------
__global__ __launch_bounds__(256) void convw_kernel(const float* __restrict__ w0,
    const float* __restrict__ w1, const float* __restrict__ w2,
    const float* __restrict__ w3, const float* __restrict__ w4, bf16* __restrict__ out) {
  int i = blockIdx.x * 256 + threadIdx.x;
  int which = i / (WELEM / 4);
  int off = (i % (WELEM / 4)) * 4;
  const float* s = which == 0 ? w0 : which == 1 ? w1 : which == 2 ? w2 : which == 3 ? w3 : w4;
  float4 v = *(const float4*)(s + off);
  bf16x4 pk;
  pk[0] = (bf16)v.x; pk[1] = (bf16)v.y; pk[2] = (bf16)v.z; pk[3] = (bf16)v.w;
  *(bf16x4*)(out + (size_t)i * 4) = pk;
}

// ---------------- GEMM body, BK=64 with XOR-swizzled LDS ------------------
// LDS[r][cg_st] holds mem cols k0 + (cg_st ^ (r&7))*8 .. +7  (cg = 8-elem colgroup)
// EPI: 0 relu->bf16, 1 plain->bf16, 2 transposed (B,H,HD,N)->bf16,
//      3 sigmoid->bf16, 4 final: Cf = X + Gate*(acc+bias) (f32)
// EPI != 2: MFMA operands swapped (computes C^T) -> packed row-major stores.
template<int EPI>
__device__ __forceinline__ void gemm_body(
    int bm, int bn, int bnl,
    const bf16* __restrict__ Aop, const bf16* __restrict__ W,
    const float* __restrict__ bias,
    bf16* __restrict__ Cb, float* __restrict__ Cf,
    const float* __restrict__ Xres, const bf16* __restrict__ Gate,
    bf16* As, bf16* Bs) {
  int tid = threadIdx.x;
  int wave = tid >> 6, lane = tid & 63;
  int quad = lane >> 4, l16 = lane & 15;
  int wm = wave & 1, wn = wave >> 1;
  int sr = lane >> 3;                 // row within 8-row chunk
  int smcg = (lane & 7) ^ sr;         // source colgroup (dest colgroup = lane&7)

  const bf16* Ag = Aop + (size_t)(bm * 128) * DD;
  const bf16* Bg = W + (size_t)(bn * 128) * DD;

  floatx4 acc[4][4];
#pragma unroll
  for (int i = 0; i < 4; i++)
#pragma unroll
    for (int j = 0; j < 4; j++)
      acc[i][j] = (floatx4){0.f, 0.f, 0.f, 0.f};

  int swzA = (l16 & 7);   // (row&7) for fragment rows (rows = mult16 + l16)

  for (int k0 = 0; k0 < DD; k0 += 64) {
    __syncthreads();
#pragma unroll
    for (int it = 0; it < 4; it++) {
      int c = it * 4 + wave;          // chunk 0..15, 8 rows each
      int row = c * 8 + sr;
      async_cp16(Ag + (size_t)row * DD + k0 + smcg * 8, &As[c * 512]);
      async_cp16(Bg + (size_t)row * DD + k0 + smcg * 8, &Bs[c * 512]);
    }
    __syncthreads();
#pragma unroll
    for (int ks = 0; ks < 2; ks++) {
      int cg = (ks * 4 + quad) ^ swzA;   // swizzled colgroup (same for A and B rows)
      bf16x8 a[4], b[4];
#pragma unroll
      for (int i = 0; i < 4; i++) a[i] = *(const bf16x8*)&As[(wm * 64 + i * 16 + l16) * 64 + cg * 8];
#pragma unroll
      for (int i = 0; i < 4; i++) b[i] = *(const bf16x8*)&Bs[(wn * 64 + i * 16 + l16) * 64 + cg * 8];
      if (EPI == 2) {
#pragma unroll
        for (int mi = 0; mi < 4; mi++)
#pragma unroll
          for (int ni = 0; ni < 4; ni++)
            acc[mi][ni] = __builtin_amdgcn_mfma_f32_16x16x32_bf16(a[mi], b[ni], acc[mi][ni], 0, 0, 0);
      } else {
#pragma unroll
        for (int mi = 0; mi < 4; mi++)
#pragma unroll
          for (int ni = 0; ni < 4; ni++)
            acc[mi][ni] = __builtin_amdgcn_mfma_f32_16x16x32_bf16(b[ni], a[mi], acc[mi][ni], 0, 0, 0);
      }
    }
  }

  if (EPI == 2) {
#pragma unroll
    for (int ni = 0; ni < 4; ni++) {
      int gc = bnl * 128 + wn * 64 + ni * 16 + l16;
      float bz = bias[gc];
      int h = gc >> 6, dd2 = gc & 63;
#pragma unroll
      for (int mi = 0; mi < 4; mi++) {
        int gm0 = bm * 128 + wm * 64 + mi * 16 + quad * 4;
        int b_ = gm0 >> 10, n0 = gm0 & 1023;
        bf16x4 pk;
#pragma unroll
        for (int r = 0; r < 4; r++) pk[r] = (bf16)(acc[mi][ni][r] + bz);
        *(bf16x4*)&Cb[(((size_t)b_ * NH + h) * HDIM + dd2) * NN + n0] = pk;
      }
    }
  } else {
#pragma unroll
    for (int mi = 0; mi < 4; mi++) {
      int gm = bm * 128 + wm * 64 + mi * 16 + l16;
#pragma unroll
      for (int ni = 0; ni < 4; ni++) {
        int gc = bnl * 128 + wn * 64 + ni * 16 + quad * 4;
        float4 bz = *(const float4*)&bias[gc];
        float v0 = acc[mi][ni][0] + bz.x;
        float v1 = acc[mi][ni][1] + bz.y;
        float v2 = acc[mi][ni][2] + bz.z;
        float v3 = acc[mi][ni][3] + bz.w;
        size_t idx = (size_t)gm * DD + gc;
        if (EPI == 4) {
          bf16x4 g = *(const bf16x4*)&Gate[idx];
          float4 xr = *(const float4*)&Xres[idx];
          float4 o;
          o.x = xr.x + (float)g[0] * v0;
          o.y = xr.y + (float)g[1] * v1;
          o.z = xr.z + (float)g[2] * v2;
          o.w = xr.w + (float)g[3] * v3;
          *(float4*)&Cf[idx] = o;
        } else {
          bf16x4 pk;
          if (EPI == 0) {
            pk[0] = (bf16)fmaxf(v0, 0.f); pk[1] = (bf16)fmaxf(v1, 0.f);
            pk[2] = (bf16)fmaxf(v2, 0.f); pk[3] = (bf16)fmaxf(v3, 0.f);
          } else if (EPI == 1) {
            pk[0] = (bf16)v0; pk[1] = (bf16)v1; pk[2] = (bf16)v2; pk[3] = (bf16)v3;
          } else {
            pk[0] = (bf16)(1.f / (1.f + __expf(-v0)));
            pk[1] = (bf16)(1.f / (1.f + __expf(-v1)));
            pk[2] = (bf16)(1.f / (1.f + __expf(-v2)));
            pk[3] = (bf16)(1.f / (1.f + __expf(-v3)));
          }
          *(bf16x4*)&Cb[idx] = pk;
        }
      }
    }
  }
}

template<int EPI_LO, int EPI_HI, int NBN>
__global__ __launch_bounds__(256) void gemm_kernel(
    const bf16* __restrict__ Aop, const bf16* __restrict__ W,
    const float* __restrict__ bias_lo, const float* __restrict__ bias_hi,
    bf16* __restrict__ C_lo, bf16* __restrict__ C_hi, float* __restrict__ Cf,
    const float* __restrict__ Xres, const bf16* __restrict__ Gate) {
  __shared__ bf16 As[128 * 64];
  __shared__ bf16 Bs[128 * 64];
  int blk = blockIdx.x;
  int xcd = blk & 7, slot = blk >> 3;
  int bm = xcd * 16 + slot / NBN;
  int bn = slot % NBN;
  if (NBN == 12 && bn >= 6) {
    gemm_body<EPI_HI>(bm, bn, bn - 6, Aop, W, bias_hi, C_hi, Cf, Xres, Gate, As, Bs);
  } else {
    gemm_body<EPI_LO>(bm, bn, bn, Aop, W, bias_lo, C_lo, Cf, Xres, Gate, As, Bs);
  }
}

// ----- RoPE + transpose: QKraw (B,N,H,HD) -> QKr (same) + QKrT (B,H,HD,N) -----
// Block = (bh, 128-n chunk). Coalesced reads, LDS-transposed, coalesced writes.
#define TLS_S 132
__global__ __launch_bounds__(256) void rope_kernel(const bf16* __restrict__ QKraw,
    const float* __restrict__ rope, bf16* __restrict__ QKr, bf16* __restrict__ QKrT) {
  __shared__ bf16 Tls[64 * TLS_S];
  int blk = blockIdx.x;
  int bh = blk >> 3, nc = blk & 7;
  int b_ = bh / NH, h_ = bh % NH;
  int nbase = nc * 128;
  int t = threadIdx.x;
  // Phase A: rows -> rope -> LDS transposed + QKr direct
  {
    int n_loc = t >> 1, ch = t & 1;
    int n = nbase + n_loc;
    const bf16* src = QKraw + ((size_t)(b_ * NN + n)) * DD + h_ * HDIM + ch * 32;
    const float* rp = rope + n * HDIM + ch * 32;
    __attribute__((aligned(16))) bf16 o1[16];
    __attribute__((aligned(16))) bf16 o2[16];
#pragma unroll
    for (int i0 = 0; i0 < 4; i0++) {
      bf16x8 v = *(const bf16x8*)(src + i0 * 8);
      float4 r0 = *(const float4*)(rp + i0 * 8);
      float4 r1 = *(const float4*)(rp + i0 * 8 + 4);
      float a0s[4] = {r0.x, r0.z, r1.x, r1.z};
      float a1s[4] = {r0.y, r0.w, r1.y, r1.w};
#pragma unroll
      for (int p = 0; p < 4; p++) {
        float x1 = (float)v[2 * p], x2 = (float)v[2 * p + 1];
        float s0, c0, s1, c1;
        __sincosf(a0s[p], &s0, &c0);
        __sincosf(a1s[p], &s1, &c1);
        int d = i0 * 4 + p;  // 0..15
        o1[d] = (bf16)(x1 * c0 - x2 * s0);
        o2[d] = (bf16)(x1 * s1 + x2 * c1);
      }
    }
    bf16* dst = QKr + ((size_t)(b_ * NN + n)) * DD + h_ * HDIM;
    *(bf16x8*)&dst[ch * 16]      = *(bf16x8*)&o1[0];
    *(bf16x8*)&dst[ch * 16 + 8]  = *(bf16x8*)&o1[8];
    *(bf16x8*)&dst[32 + ch * 16]     = *(bf16x8*)&o2[0];
    *(bf16x8*)&dst[32 + ch * 16 + 8] = *(bf16x8*)&o2[8];
#pragma unroll
    for (int d = 0; d < 16; d++) {
      Tls[(ch * 16 + d) * TLS_S + n_loc] = o1[d];
      Tls[(32 + ch * 16 + d) * TLS_S + n_loc] = o2[d];
    }
  }
  __syncthreads();
  // Phase B: coalesced QKrT writes
  {
    int c = t >> 2, qn = t & 3;
    __attribute__((aligned(16))) bf16 buf[32];
#pragma unroll
    for (int j = 0; j < 8; j++)
      *(bf16x4*)&buf[j * 4] = *(const bf16x4*)&Tls[c * TLS_S + qn * 32 + j * 4];
    bf16* dst = QKrT + ((size_t)bh * HDIM + c) * NN + nbase + qn * 32;
#pragma unroll
    for (int j = 0; j < 4; j++)
      *(bf16x8*)&dst[j * 8] = *(bf16x8*)&buf[j * 8];
  }
}

// ---- Attention: T = QKr^T @ V (64x64, recomputed per quarter), attn = QKr @ T / 8
// 768 blocks: xcd-swizzled (bh, quarter) so all 4 quarters of a bh share an XCD L2.
__global__ __launch_bounds__(256) void attn_kernel(const bf16* __restrict__ QKr,
    const bf16* __restrict__ QKrT, const bf16* __restrict__ VT, bf16* __restrict__ attn) {
  __shared__ float Tp[64][64];
  __shared__ bf16 Tbf[64][72];
  int blk = blockIdx.x;
  int xcd = blk & 7, s = blk >> 3;
  int bhl = s >> 2, q = s & 3;
  int bh = xcd * 24 + bhl;
  int tid = threadIdx.x, wave = tid >> 6, lane = tid & 63;
  int quad = lane >> 4, l16 = lane & 15;
  const bf16* Qt = QKrT + (size_t)bh * (HDIM * NN);
  const bf16* Vt = VT + (size_t)bh * (HDIM * NN);

  floatx4 acc[4][4];
#pragma unroll
  for (int i = 0; i < 4; i++)
#pragma unroll
    for (int j = 0; j < 4; j++)
      acc[i][j] = (floatx4){0.f, 0.f, 0.f, 0.f};

  int kbase = wave * 256;
#pragma unroll
  for (int k0 = 0; k0 < 256; k0 += 32) {
    bf16x8 a[4], b[4];
#pragma unroll
    for (int i = 0; i < 4; i++) a[i] = *(const bf16x8*)&Qt[(size_t)(i * 16 + l16) * NN + kbase + k0 + quad * 8];
#pragma unroll
    for (int i = 0; i < 4; i++) b[i] = *(const bf16x8*)&Vt[(size_t)(i * 16 + l16) * NN + kbase + k0 + quad * 8];
#pragma unroll
    for (int mi = 0; mi < 4; mi++)
#pragma unroll
      for (int ni = 0; ni < 4; ni++)
        acc[mi][ni] = __builtin_amdgcn_mfma_f32_16x16x32_bf16(a[mi], b[ni], acc[mi][ni], 0, 0, 0);
  }
#pragma unroll
  for (int w = 0; w < 4; w++) {
    if (wave == w) {
#pragma unroll
      for (int mi = 0; mi < 4; mi++)
#pragma unroll
        for (int ni = 0; ni < 4; ni++)
#pragma unroll
          for (int r = 0; r < 4; r++) {
            float val = acc[mi][ni][r];
            float* p = &Tp[mi * 16 + quad * 4 + r][ni * 16 + l16];
            if (w == 0) *p = val; else *p += val;
          }
    }
    __syncthreads();
  }
  for (int e = tid; e < 4096; e += 256) {
    int d1 = e >> 6, d2 = e & 63;
    Tbf[d2][d1] = (bf16)(Tp[d1][d2] * 0.125f);
  }
  __syncthreads();

  int b_ = bh / NH, h_ = bh % NH;
  const bf16* Q = QKr + (size_t)(b_ * NN) * DD + h_ * HDIM;
  bf16* Ao = attn + (size_t)(b_ * NN) * DD + h_ * HDIM;
  bf16x8 Bf[4][2];
#pragma unroll
  for (int ni = 0; ni < 4; ni++)
#pragma unroll
    for (int ks = 0; ks < 2; ks++)
      Bf[ni][ks] = *(const bf16x8*)&Tbf[ni * 16 + l16][ks * 32 + quad * 8];

#pragma unroll
  for (int mi = 0; mi < 4; mi++) {
    int nrow = q * 256 + wave * 64 + mi * 16;
    bf16x8 a0 = *(const bf16x8*)&Q[(size_t)(nrow + l16) * DD + quad * 8];
    bf16x8 a1 = *(const bf16x8*)&Q[(size_t)(nrow + l16) * DD + 32 + quad * 8];
    floatx4 o[4];
#pragma unroll
    for (int ni = 0; ni < 4; ni++) o[ni] = (floatx4){0.f, 0.f, 0.f, 0.f};
#pragma unroll
    for (int ni = 0; ni < 4; ni++) {
      o[ni] = __builtin_amdgcn_mfma_f32_16x16x32_bf16(a0, Bf[ni][0], o[ni], 0, 0, 0);
      o[ni] = __builtin_amdgcn_mfma_f32_16x16x32_bf16(a1, Bf[ni][1], o[ni], 0, 0, 0);
    }
#pragma unroll
    for (int ni = 0; ni < 4; ni++)
#pragma unroll
      for (int r = 0; r < 4; r++)
        Ao[(size_t)(nrow + quad * 4 + r) * DD + ni * 16 + l16] = (bf16)o[ni][r];
  }
}

extern "C" void kernel_launch(void* const* d_in, const int* in_sizes, int n_in,
                              void* d_out, int out_size, void* d_ws, size_t ws_size,
                              hipStream_t stream) {
  const float* x      = (const float*)d_in[0];
  const float* rope   = (const float*)d_in[1];
  const float* ln_w   = (const float*)d_in[2];
  const float* ln_b   = (const float*)d_in[3];
  const float* enc_w  = (const float*)d_in[4];
  const float* enc_b  = (const float*)d_in[5];
  const float* qk_w   = (const float*)d_in[6];
  const float* qk_b   = (const float*)d_in[7];
  const float* v_w    = (const float*)d_in[8];
  const float* v_b    = (const float*)d_in[9];
  const float* out_w  = (const float*)d_in[10];
  const float* out_b  = (const float*)d_in[11];
  const float* gate_w = (const float*)d_in[12];
  const float* gate_b = (const float*)d_in[13];

  char* w = (char*)d_ws;
  const size_t S = (size_t)MTOT * DD * 2;
  bf16* s0 = (bf16*)(w);
  bf16* s1 = (bf16*)(w + S);
  bf16* s2 = (bf16*)(w + 2 * S);
  bf16* s3 = (bf16*)(w + 3 * S);
  bf16* s4 = (bf16*)(w + 4 * S);
  bf16* s5 = (bf16*)(w + 5 * S);
  bf16* Wb = (bf16*)(w + 6 * S);

  bf16* A = s0;
  bf16* L = s1;
  bf16* Gate = s2;
  bf16* QKraw = s0;
  bf16* QKr = s3;
  bf16* QKrT = s4;
  bf16* VT = s5;
  bf16* attnb = s1;

  ln_kernel<<<dim3(MTOT / 4), dim3(256), 0, stream>>>(x, ln_w, ln_b, A);
  convw_kernel<<<dim3(5 * WELEM / 4 / 256), dim3(256), 0, stream>>>(enc_w, gate_w, qk_w, v_w, out_w, Wb);

  gemm_kernel<0, 3, 12><<<dim3(1536), dim3(256), 0, stream>>>(
      A, Wb, enc_b, gate_b, L, Gate, nullptr, nullptr, nullptr);
  gemm_kernel<1, 2, 12><<<dim3(1536), dim3(256), 0, stream>>>(
      L, Wb + 2 * (size_t)WELEM, qk_b, v_b, QKraw, VT, nullptr, nullptr, nullptr);
  rope_kernel<<<dim3(BB * NH * 8), dim3(256), 0, stream>>>(QKraw, rope, QKr, QKrT);
  attn_kernel<<<dim3(BB * NH * 4), dim3(256), 0, stream>>>(QKr, QKrT, VT, attnb);
  gemm_kernel<4, 4, 6><<<dim3(768), dim3(256), 0, stream>>>(
      attnb, Wb + 4 * (size_t)WELEM, out_b, nullptr, nullptr, nullptr, (float*)d_out, x, Gate);
}

// Round 4
// 333.130 us; speedup vs baseline: 1.1678x; 1.0199x over previous
//
#include <hip/hip_runtime.h>

typedef __bf16 bf16;
typedef __bf16 bf16x4 __attribute__((ext_vector_type(4)));
typedef __bf16 bf16x8 __attribute__((ext_vector_type(8)));
typedef float floatx4 __attribute__((ext_vector_type(4)));

#define DD 768
#define NH 12
#define HDIM 64
#define BB 16
#define NN 1024
#define MTOT (BB*NN)   // 16384
#define WELEM (DD*DD)  // 589824

__device__ __forceinline__ void async_cp16(const void* g, void* l) {
  __builtin_amdgcn_global_load_lds((const __attribute__((address_space(1))) void*)g,
                                   (__attribute__((address_space(3))) void*)l, 16, 0, 0);
}

// ---------------- LayerNorm: x (f32) -> A (bf16) ----------------
__global__ __launch_bounds__(256) void ln_kernel(const float* __restrict__ x,
    const float* __restrict__ w, const float* __restrict__ b, bf16* __restrict__ A) {
  int row = blockIdx.x * 4 + (threadIdx.x >> 6);
  int lane = threadIdx.x & 63;
  const float4* xr = (const float4*)(x + (size_t)row * DD);
  float4 v[3];
  float s = 0.f;
#pragma unroll
  for (int i = 0; i < 3; i++) {
    v[i] = xr[lane + 64 * i];
    s += v[i].x + v[i].y + v[i].z + v[i].w;
  }
#pragma unroll
  for (int o = 32; o; o >>= 1) s += __shfl_xor(s, o);
  float mu = s * (1.f / 768.f);
  float vs = 0.f;
#pragma unroll
  for (int i = 0; i < 3; i++) {
    float dx;
    dx = v[i].x - mu; vs += dx * dx;
    dx = v[i].y - mu; vs += dx * dx;
    dx = v[i].z - mu; vs += dx * dx;
    dx = v[i].w - mu; vs += dx * dx;
  }
#pragma unroll
  for (int o = 32; o; o >>= 1) vs += __shfl_xor(vs, o);
  float rstd = rsqrtf(vs * (1.f / 768.f) + 1e-5f);
  const float4* wv = (const float4*)w;
  const float4* bv = (const float4*)b;
  bf16* Ar = A + (size_t)row * DD;
#pragma unroll
  for (int i = 0; i < 3; i++) {
    int c4 = lane + 64 * i;
    float4 ww = wv[c4], bb = bv[c4];
    bf16x4 pk;
    pk[0] = (bf16)((v[i].x - mu) * rstd * ww.x + bb.x);
    pk[1] = (bf16)((v[i].y - mu) * rstd * ww.y + bb.y);
    pk[2] = (bf16)((v[i].z - mu) * rstd * ww.z + bb.z);
    pk[3] = (bf16)((v[i].w - mu) * rstd * ww.w + bb.w);
    *(bf16x4*)(Ar + c4 * 4) = pk;
  }
}

// ------- Convert weights f32 -> bf16, order: enc, gate, qk, v, out -------
__global__ __launch_bounds__(256) void convw_kernel(const float* __restrict__ w0,
    const float* __restrict__ w1, const float* __restrict__ w2,
    const float* __restrict__ w3, const float* __restrict__ w4, bf16* __restrict__ out) {
  int i = blockIdx.x * 256 + threadIdx.x;
  int which = i / (WELEM / 4);
  int off = (i % (WELEM / 4)) * 4;
  const float* s = which == 0 ? w0 : which == 1 ? w1 : which == 2 ? w2 : which == 3 ? w3 : w4;
  float4 v = *(const float4*)(s + off);
  bf16x4 pk;
  pk[0] = (bf16)v.x; pk[1] = (bf16)v.y; pk[2] = (bf16)v.z; pk[3] = (bf16)v.w;
  *(bf16x4*)(out + (size_t)i * 4) = pk;
}

// -------- GEMM body: 256x128 block tile, 128x64 per wave (8x4 acc), BK=64 -----
// XOR-swizzled LDS: LDS[r][cg_st] holds mem colgroup (cg_st ^ (r&7)).
// EPI: 0 relu->bf16, 1 plain->bf16, 2 transposed (B,H,HD,N)->bf16,
//      3 sigmoid->bf16, 4 final: Cf = X + Gate*(acc+bias) (f32)
// EPI != 2: MFMA operands swapped (computes C^T) -> packed row-major stores.
template<int EPI>
__device__ __forceinline__ void gemm_body(
    int bm, int bn, int bnl,
    const bf16* __restrict__ Aop, const bf16* __restrict__ W,
    const float* __restrict__ bias,
    bf16* __restrict__ Cb, float* __restrict__ Cf,
    const float* __restrict__ Xres, const bf16* __restrict__ Gate,
    bf16* As, bf16* Bs) {
  int tid = threadIdx.x;
  int wave = tid >> 6, lane = tid & 63;
  int quad = lane >> 4, l16 = lane & 15;
  int wm = wave & 1, wn = wave >> 1;
  int sr = lane >> 3;                 // row within 8-row chunk
  int smcg = (lane & 7) ^ sr;         // source colgroup (dest colgroup = lane&7)

  const bf16* Ag = Aop + (size_t)(bm * 256) * DD;
  const bf16* Bg = W + (size_t)(bn * 128) * DD;

  floatx4 acc[8][4];
#pragma unroll
  for (int i = 0; i < 8; i++)
#pragma unroll
    for (int j = 0; j < 4; j++)
      acc[i][j] = (floatx4){0.f, 0.f, 0.f, 0.f};

  int swzA = (l16 & 7);

  for (int k0 = 0; k0 < DD; k0 += 64) {
    __syncthreads();
#pragma unroll
    for (int it = 0; it < 8; it++) {     // A: 32 chunks of 8 rows
      int c = it * 4 + wave;
      int row = c * 8 + sr;
      async_cp16(Ag + (size_t)row * DD + k0 + smcg * 8, &As[c * 512]);
    }
#pragma unroll
    for (int it = 0; it < 4; it++) {     // B: 16 chunks of 8 rows
      int c = it * 4 + wave;
      int row = c * 8 + sr;
      async_cp16(Bg + (size_t)row * DD + k0 + smcg * 8, &Bs[c * 512]);
    }
    __syncthreads();
#pragma unroll
    for (int ks = 0; ks < 2; ks++) {
      int cg = (ks * 4 + quad) ^ swzA;
      bf16x8 a[8], b[4];
#pragma unroll
      for (int i = 0; i < 8; i++) a[i] = *(const bf16x8*)&As[(wm * 128 + i * 16 + l16) * 64 + cg * 8];
#pragma unroll
      for (int i = 0; i < 4; i++) b[i] = *(const bf16x8*)&Bs[(wn * 64 + i * 16 + l16) * 64 + cg * 8];
      if (EPI == 2) {
#pragma unroll
        for (int mi = 0; mi < 8; mi++)
#pragma unroll
          for (int ni = 0; ni < 4; ni++)
            acc[mi][ni] = __builtin_amdgcn_mfma_f32_16x16x32_bf16(a[mi], b[ni], acc[mi][ni], 0, 0, 0);
      } else {
#pragma unroll
        for (int mi = 0; mi < 8; mi++)
#pragma unroll
          for (int ni = 0; ni < 4; ni++)
            acc[mi][ni] = __builtin_amdgcn_mfma_f32_16x16x32_bf16(b[ni], a[mi], acc[mi][ni], 0, 0, 0);
      }
    }
  }

  if (EPI == 2) {
#pragma unroll
    for (int ni = 0; ni < 4; ni++) {
      int gc = bnl * 128 + wn * 64 + ni * 16 + l16;
      float bz = bias[gc];
      int h = gc >> 6, dd2 = gc & 63;
#pragma unroll
      for (int mi = 0; mi < 8; mi++) {
        int gm0 = bm * 256 + wm * 128 + mi * 16 + quad * 4;
        int b_ = gm0 >> 10, n0 = gm0 & 1023;
        bf16x4 pk;
#pragma unroll
        for (int r = 0; r < 4; r++) pk[r] = (bf16)(acc[mi][ni][r] + bz);
        *(bf16x4*)&Cb[(((size_t)b_ * NH + h) * HDIM + dd2) * NN + n0] = pk;
      }
    }
  } else {
#pragma unroll
    for (int mi = 0; mi < 8; mi++) {
      int gm = bm * 256 + wm * 128 + mi * 16 + l16;
#pragma unroll
      for (int ni = 0; ni < 4; ni++) {
        int gc = bnl * 128 + wn * 64 + ni * 16 + quad * 4;
        float4 bz = *(const float4*)&bias[gc];
        float v0 = acc[mi][ni][0] + bz.x;
        float v1 = acc[mi][ni][1] + bz.y;
        float v2 = acc[mi][ni][2] + bz.z;
        float v3 = acc[mi][ni][3] + bz.w;
        size_t idx = (size_t)gm * DD + gc;
        if (EPI == 4) {
          bf16x4 g = *(const bf16x4*)&Gate[idx];
          float4 xr = *(const float4*)&Xres[idx];
          float4 o;
          o.x = xr.x + (float)g[0] * v0;
          o.y = xr.y + (float)g[1] * v1;
          o.z = xr.z + (float)g[2] * v2;
          o.w = xr.w + (float)g[3] * v3;
          *(float4*)&Cf[idx] = o;
        } else {
          bf16x4 pk;
          if (EPI == 0) {
            pk[0] = (bf16)fmaxf(v0, 0.f); pk[1] = (bf16)fmaxf(v1, 0.f);
            pk[2] = (bf16)fmaxf(v2, 0.f); pk[3] = (bf16)fmaxf(v3, 0.f);
          } else if (EPI == 1) {
            pk[0] = (bf16)v0; pk[1] = (bf16)v1; pk[2] = (bf16)v2; pk[3] = (bf16)v3;
          } else {
            pk[0] = (bf16)(1.f / (1.f + __expf(-v0)));
            pk[1] = (bf16)(1.f / (1.f + __expf(-v1)));
            pk[2] = (bf16)(1.f / (1.f + __expf(-v2)));
            pk[3] = (bf16)(1.f / (1.f + __expf(-v3)));
          }
          *(bf16x4*)&Cb[idx] = pk;
        }
      }
    }
  }
}

// bm count = MTOT/256 = 64; xcd owns 8 bm. Grid = 64 * NBN.
template<int EPI_LO, int EPI_HI, int NBN>
__global__ __launch_bounds__(256, 2) void gemm_kernel(
    const bf16* __restrict__ Aop, const bf16* __restrict__ W,
    const float* __restrict__ bias_lo, const float* __restrict__ bias_hi,
    bf16* __restrict__ C_lo, bf16* __restrict__ C_hi, float* __restrict__ Cf,
    const float* __restrict__ Xres, const bf16* __restrict__ Gate) {
  __shared__ bf16 As[256 * 64];
  __shared__ bf16 Bs[128 * 64];
  int blk = blockIdx.x;
  int xcd = blk & 7, slot = blk >> 3;
  int bm = xcd * 8 + slot / NBN;
  int bn = slot % NBN;
  if (NBN == 12 && bn >= 6) {
    gemm_body<EPI_HI>(bm, bn, bn - 6, Aop, W, bias_hi, C_hi, Cf, Xres, Gate, As, Bs);
  } else {
    gemm_body<EPI_LO>(bm, bn, bn, Aop, W, bias_lo, C_lo, Cf, Xres, Gate, As, Bs);
  }
}

// ----- RoPE + transpose: QKraw (B,N,H,HD) -> QKr (same) + QKrT (B,H,HD,N) -----
#define TLS_S 132
__global__ __launch_bounds__(256) void rope_kernel(const bf16* __restrict__ QKraw,
    const float* __restrict__ rope, bf16* __restrict__ QKr, bf16* __restrict__ QKrT) {
  __shared__ bf16 Tls[64 * TLS_S];
  int blk = blockIdx.x;
  int bh = blk >> 3, nc = blk & 7;
  int b_ = bh / NH, h_ = bh % NH;
  int nbase = nc * 128;
  int t = threadIdx.x;
  {
    int n_loc = t >> 1, ch = t & 1;
    int n = nbase + n_loc;
    const bf16* src = QKraw + ((size_t)(b_ * NN + n)) * DD + h_ * HDIM + ch * 32;
    const float* rp = rope + n * HDIM + ch * 32;
    __attribute__((aligned(16))) bf16 o1[16];
    __attribute__((aligned(16))) bf16 o2[16];
#pragma unroll
    for (int i0 = 0; i0 < 4; i0++) {
      bf16x8 v = *(const bf16x8*)(src + i0 * 8);
      float4 r0 = *(const float4*)(rp + i0 * 8);
      float4 r1 = *(const float4*)(rp + i0 * 8 + 4);
      float a0s[4] = {r0.x, r0.z, r1.x, r1.z};
      float a1s[4] = {r0.y, r0.w, r1.y, r1.w};
#pragma unroll
      for (int p = 0; p < 4; p++) {
        float x1 = (float)v[2 * p], x2 = (float)v[2 * p + 1];
        float s0, c0, s1, c1;
        __sincosf(a0s[p], &s0, &c0);
        __sincosf(a1s[p], &s1, &c1);
        int d = i0 * 4 + p;
        o1[d] = (bf16)(x1 * c0 - x2 * s0);
        o2[d] = (bf16)(x1 * s1 + x2 * c1);
      }
    }
    bf16* dst = QKr + ((size_t)(b_ * NN + n)) * DD + h_ * HDIM;
    *(bf16x8*)&dst[ch * 16]      = *(bf16x8*)&o1[0];
    *(bf16x8*)&dst[ch * 16 + 8]  = *(bf16x8*)&o1[8];
    *(bf16x8*)&dst[32 + ch * 16]     = *(bf16x8*)&o2[0];
    *(bf16x8*)&dst[32 + ch * 16 + 8] = *(bf16x8*)&o2[8];
#pragma unroll
    for (int d = 0; d < 16; d++) {
      Tls[(ch * 16 + d) * TLS_S + n_loc] = o1[d];
      Tls[(32 + ch * 16 + d) * TLS_S + n_loc] = o2[d];
    }
  }
  __syncthreads();
  {
    int c = t >> 2, qn = t & 3;
    __attribute__((aligned(16))) bf16 buf[32];
#pragma unroll
    for (int j = 0; j < 8; j++)
      *(bf16x4*)&buf[j * 4] = *(const bf16x4*)&Tls[c * TLS_S + qn * 32 + j * 4];
    bf16* dst = QKrT + ((size_t)bh * HDIM + c) * NN + nbase + qn * 32;
#pragma unroll
    for (int j = 0; j < 4; j++)
      *(bf16x8*)&dst[j * 8] = *(bf16x8*)&buf[j * 8];
  }
}

// ---- Attention: T = QKr^T @ V (64x64, recomputed per quarter), attn = QKr @ T / 8
__global__ __launch_bounds__(256) void attn_kernel(const bf16* __restrict__ QKr,
    const bf16* __restrict__ QKrT, const bf16* __restrict__ VT, bf16* __restrict__ attn) {
  __shared__ float Tp[64][64];
  __shared__ bf16 Tbf[64][72];
  int blk = blockIdx.x;
  int xcd = blk & 7, s = blk >> 3;
  int bhl = s >> 2, q = s & 3;
  int bh = xcd * 24 + bhl;
  int tid = threadIdx.x, wave = tid >> 6, lane = tid & 63;
  int quad = lane >> 4, l16 = lane & 15;
  const bf16* Qt = QKrT + (size_t)bh * (HDIM * NN);
  const bf16* Vt = VT + (size_t)bh * (HDIM * NN);

  floatx4 acc[4][4];
#pragma unroll
  for (int i = 0; i < 4; i++)
#pragma unroll
    for (int j = 0; j < 4; j++)
      acc[i][j] = (floatx4){0.f, 0.f, 0.f, 0.f};

  int kbase = wave * 256;
#pragma unroll
  for (int k0 = 0; k0 < 256; k0 += 32) {
    bf16x8 a[4], b[4];
#pragma unroll
    for (int i = 0; i < 4; i++) a[i] = *(const bf16x8*)&Qt[(size_t)(i * 16 + l16) * NN + kbase + k0 + quad * 8];
#pragma unroll
    for (int i = 0; i < 4; i++) b[i] = *(const bf16x8*)&Vt[(size_t)(i * 16 + l16) * NN + kbase + k0 + quad * 8];
#pragma unroll
    for (int mi = 0; mi < 4; mi++)
#pragma unroll
      for (int ni = 0; ni < 4; ni++)
        acc[mi][ni] = __builtin_amdgcn_mfma_f32_16x16x32_bf16(a[mi], b[ni], acc[mi][ni], 0, 0, 0);
  }
#pragma unroll
  for (int w = 0; w < 4; w++) {
    if (wave == w) {
#pragma unroll
      for (int mi = 0; mi < 4; mi++)
#pragma unroll
        for (int ni = 0; ni < 4; ni++)
#pragma unroll
          for (int r = 0; r < 4; r++) {
            float val = acc[mi][ni][r];
            float* p = &Tp[mi * 16 + quad * 4 + r][ni * 16 + l16];
            if (w == 0) *p = val; else *p += val;
          }
    }
    __syncthreads();
  }
  for (int e = tid; e < 4096; e += 256) {
    int d1 = e >> 6, d2 = e & 63;
    Tbf[d2][d1] = (bf16)(Tp[d1][d2] * 0.125f);
  }
  __syncthreads();

  int b_ = bh / NH, h_ = bh % NH;
  const bf16* Q = QKr + (size_t)(b_ * NN) * DD + h_ * HDIM;
  bf16* Ao = attn + (size_t)(b_ * NN) * DD + h_ * HDIM;
  bf16x8 Bf[4][2];
#pragma unroll
  for (int ni = 0; ni < 4; ni++)
#pragma unroll
    for (int ks = 0; ks < 2; ks++)
      Bf[ni][ks] = *(const bf16x8*)&Tbf[ni * 16 + l16][ks * 32 + quad * 8];

#pragma unroll
  for (int mi = 0; mi < 4; mi++) {
    int nrow = q * 256 + wave * 64 + mi * 16;
    bf16x8 a0 = *(const bf16x8*)&Q[(size_t)(nrow + l16) * DD + quad * 8];
    bf16x8 a1 = *(const bf16x8*)&Q[(size_t)(nrow + l16) * DD + 32 + quad * 8];
    floatx4 o[4];
#pragma unroll
    for (int ni = 0; ni < 4; ni++) o[ni] = (floatx4){0.f, 0.f, 0.f, 0.f};
#pragma unroll
    for (int ni = 0; ni < 4; ni++) {
      o[ni] = __builtin_amdgcn_mfma_f32_16x16x32_bf16(a0, Bf[ni][0], o[ni], 0, 0, 0);
      o[ni] = __builtin_amdgcn_mfma_f32_16x16x32_bf16(a1, Bf[ni][1], o[ni], 0, 0, 0);
    }
#pragma unroll
    for (int ni = 0; ni < 4; ni++)
#pragma unroll
      for (int r = 0; r < 4; r++)
        Ao[(size_t)(nrow + quad * 4 + r) * DD + ni * 16 + l16] = (bf16)o[ni][r];
  }
}

extern "C" void kernel_launch(void* const* d_in, const int* in_sizes, int n_in,
                              void* d_out, int out_size, void* d_ws, size_t ws_size,
                              hipStream_t stream) {
  const float* x      = (const float*)d_in[0];
  const float* rope   = (const float*)d_in[1];
  const float* ln_w   = (const float*)d_in[2];
  const float* ln_b   = (const float*)d_in[3];
  const float* enc_w  = (const float*)d_in[4];
  const float* enc_b  = (const float*)d_in[5];
  const float* qk_w   = (const float*)d_in[6];
  const float* qk_b   = (const float*)d_in[7];
  const float* v_w    = (const float*)d_in[8];
  const float* v_b    = (const float*)d_in[9];
  const float* out_w  = (const float*)d_in[10];
  const float* out_b  = (const float*)d_in[11];
  const float* gate_w = (const float*)d_in[12];
  const float* gate_b = (const float*)d_in[13];

  char* w = (char*)d_ws;
  const size_t S = (size_t)MTOT * DD * 2;
  bf16* s0 = (bf16*)(w);
  bf16* s1 = (bf16*)(w + S);
  bf16* s2 = (bf16*)(w + 2 * S);
  bf16* s3 = (bf16*)(w + 3 * S);
  bf16* s4 = (bf16*)(w + 4 * S);
  bf16* s5 = (bf16*)(w + 5 * S);
  bf16* Wb = (bf16*)(w + 6 * S);

  bf16* A = s0;
  bf16* L = s1;
  bf16* Gate = s2;
  bf16* QKraw = s0;
  bf16* QKr = s3;
  bf16* QKrT = s4;
  bf16* VT = s5;
  bf16* attnb = s1;

  ln_kernel<<<dim3(MTOT / 4), dim3(256), 0, stream>>>(x, ln_w, ln_b, A);
  convw_kernel<<<dim3(5 * WELEM / 4 / 256), dim3(256), 0, stream>>>(enc_w, gate_w, qk_w, v_w, out_w, Wb);

  gemm_kernel<0, 3, 12><<<dim3(768), dim3(256), 0, stream>>>(
      A, Wb, enc_b, gate_b, L, Gate, nullptr, nullptr, nullptr);
  gemm_kernel<1, 2, 12><<<dim3(768), dim3(256), 0, stream>>>(
      L, Wb + 2 * (size_t)WELEM, qk_b, v_b, QKraw, VT, nullptr, nullptr, nullptr);
  rope_kernel<<<dim3(BB * NH * 8), dim3(256), 0, stream>>>(QKraw, rope, QKr, QKrT);
  attn_kernel<<<dim3(BB * NH * 4), dim3(256), 0, stream>>>(QKr, QKrT, VT, attnb);
  gemm_kernel<4, 4, 6><<<dim3(384), dim3(256), 0, stream>>>(
      attnb, Wb + 4 * (size_t)WELEM, out_b, nullptr, nullptr, nullptr, (float*)d_out, x, Gate);
}